// Round 6
// baseline (256.668 us; speedup 1.0000x reference)
//
#include <hip/hip_runtime.h>
#include <float.h>

typedef __attribute__((ext_vector_type(8))) short short8;
typedef __attribute__((ext_vector_type(4))) float f32x4;

#define BT    16384      // B*T tokens
#define DM    256        // embedding dim
#define KC    8192       // codebook size
#define QOFF  (BT * DM)  // start of indices in d_out
#define LOFF  (QOFF + BT)
#define MARGIN 2e-4f

// ws layout (ushort elems): bf16 x and codebook
#define E_XH 0
#define E_CH (BT * DM)
#define WS_LP_BYTES ((size_t)(BT * DM + KC * DM) * 2)   // 12582912
#define WS_NEED (WS_LP_BYTES + 4096 * 4)

// ======================= MFMA path =======================

__device__ inline ushort bf16rne(float f) {
    unsigned u = __float_as_uint(f);
    return (ushort)((u + 0x7FFFu + ((u >> 16) & 1u)) >> 16);
}

// k_cvt: one-time bf16 round of x and codebook into ws
__global__ __launch_bounds__(256) void k_cvt(const float* __restrict__ x,
                                             const float* __restrict__ cb,
                                             ushort* __restrict__ ws) {
    const int XN = BT * DM / 4;   // 1048576 float4s
    const int CN = KC * DM / 4;   // 524288
    int idx = blockIdx.x * 256 + threadIdx.x;
    const float4* src;
    ushort* dh; int o;
    if (idx < XN) { src = (const float4*)x; dh = ws + E_XH; o = idx; }
    else {
        o = idx - XN;
        if (o >= CN) return;
        src = (const float4*)cb; dh = ws + E_CH;
    }
    float4 v = src[o];
    ushort4 h;
    h.x = bf16rne(v.x);
    h.y = bf16rne(v.y);
    h.z = bf16rne(v.z);
    h.w = bf16rne(v.w);
    ((ushort4*)dh)[o] = h;
}

// k_main_mfma v5: code-stationary. grid 512 = 64 code-groups x 8 token-chunks
// (chunk = bid&7 = XCD -> 1MB token chunk L2-resident per XCD).
// Block: 256 thr / 4 waves, 2 blocks/CU. Wave w holds codes
// grp*128+w*32 .. +32 x full D=256 in 64 VGPRs (a[2][8] short8, loaded once).
// Token panels (64 tok x 256 d = 32 KB) stream via double-buffered LDS with
// the R4-verified zero-conflict XOR layout; T14 reg-staged async split.
// Per panel: per-token top-2 over the block's 128 codes -> out slot = grp.
__global__ __launch_bounds__(256, 2) void k_main_mfma(const ushort* __restrict__ ws,
                                                      float* __restrict__ out) {
    __shared__ ushort sTok[2][64 * 256];   // 2 x 32 KB token panels
    __shared__ float4 msc[2][64][4];       // 8 KB cross-wave merge scratch

    const int tid = threadIdx.x;
    const int w = tid >> 6, L = tid & 63;
    const int lq = L >> 4, lr = L & 15;
    const int grp   = blockIdx.x >> 3;       // code group 0..63
    const int chunk = blockIdx.x & 7;        // token chunk (== XCD slot)
    const int c0w   = grp * 128 + w * 32;    // wave's first code
    const int tok0  = chunk * 2048;

    const short8* ch8 = (const short8*)(ws + E_CH);
    const uint4*  xh4 = (const uint4*)(ws + E_XH);

    // ---- A (codes) register-resident: a[i][ks] = codes c0w+i*16+lr, k=ks*32+lq*8..+8
    short8 a[2][8];
    #pragma unroll
    for (int i = 0; i < 2; ++i)
        #pragma unroll
        for (int ks = 0; ks < 8; ++ks)
            a[i][ks] = ch8[(size_t)(c0w + i * 16 + lr) * 32 + ks * 4 + lq];

    const int srow = tid >> 5;   // staging row-in-8
    const int sg   = tid & 31;   // staging granule 0..31

    // ---- prologue: stage panel 0 into buf 0
    uint4 st[8];
    #pragma unroll
    for (int q = 0; q < 8; ++q) {
        int row = q * 8 + srow;
        st[q] = xh4[(size_t)(tok0 + row) * 32 + sg];
    }
    #pragma unroll
    for (int q = 0; q < 8; ++q) {
        int row = q * 8 + srow;
        *(uint4*)&sTok[0][row * 256 + ((sg ^ (row & 7)) * 8)] = st[q];
    }
    __syncthreads();

    for (int p = 0; p < 32; ++p) {
        const int cur = p & 1;

        // issue next-panel global loads early (latency hides under compute)
        if (p + 1 < 32) {
            #pragma unroll
            for (int q = 0; q < 8; ++q) {
                int row = q * 8 + srow;
                st[q] = xh4[(size_t)(tok0 + (p + 1) * 64 + row) * 32 + sg];
            }
        }

        // ---- compute panel p: 8 K=32 steps, A from regs, B from LDS
        f32x4 acc[2][4];
        #pragma unroll
        for (int i = 0; i < 2; ++i)
            #pragma unroll
            for (int j = 0; j < 4; ++j) acc[i][j] = (f32x4){0.f, 0.f, 0.f, 0.f};

        const ushort* tb = &sTok[cur][0];
        #pragma unroll
        for (int ks = 0; ks < 8; ++ks) {
            short8 b[4];
            #pragma unroll
            for (int j = 0; j < 4; ++j) {
                int row = j * 16 + lr;
                b[j] = *(const short8*)(tb + row * 256 + (((ks * 4 + lq) ^ (lr & 7)) * 8));
            }
            #pragma unroll
            for (int i = 0; i < 2; ++i)
                #pragma unroll
                for (int j = 0; j < 4; ++j)
                    acc[i][j] = __builtin_amdgcn_mfma_f32_16x16x32_bf16(a[i][ks], b[j], acc[i][j], 0, 0, 0);
        }

        // ---- fold: per (lane, token frag j) top-2 over 8 (i,r); merge over lq
        #pragma unroll
        for (int j = 0; j < 4; ++j) {
            float v1 = -FLT_MAX, v2 = -FLT_MAX; int k1 = 0, k2 = 0;
            #pragma unroll
            for (int i = 0; i < 2; ++i)
                #pragma unroll
                for (int r = 0; r < 4; ++r) {
                    float d = acc[i][j][r];
                    int kk = c0w + i * 16 + lq * 4 + r;
                    if (d > v2) {
                        if (d > v1) { v2 = v1; k2 = k1; v1 = d; k1 = kk; }
                        else        { v2 = d; k2 = kk; }
                    }
                }
            #pragma unroll
            for (int off = 16; off <= 32; off <<= 1) {
                float o1 = __shfl_xor(v1, off), o2 = __shfl_xor(v2, off);
                int   p1 = __shfl_xor(k1, off), p2 = __shfl_xor(k2, off);
                bool oB = (o1 > v1) || (o1 == v1 && p1 < k1);
                float n1, n2; int q1, q2;
                if (oB) {
                    n1 = o1; q1 = p1;
                    bool t2 = (v1 > o2) || (v1 == o2 && k1 < p2);
                    n2 = t2 ? v1 : o2; q2 = t2 ? k1 : p2;
                } else {
                    n1 = v1; q1 = k1;
                    bool t2 = (o1 > v2) || (o1 == v2 && p1 < k2);
                    n2 = t2 ? o1 : v2; q2 = t2 ? p1 : k2;
                }
                v1 = n1; v2 = n2; k1 = q1; k2 = q2;
            }
            if (lq == 0)
                msc[cur][j * 16 + lr][w] = (float4){ v1, (float)k1, v2, (float)k2 };
        }
        __syncthreads();   // msc visible; panel p-1's reads of buf[cur^1] long done

        // ---- write staged regs into the other buffer (vmcnt wait auto-inserted)
        if (p + 1 < 32) {
            #pragma unroll
            for (int q = 0; q < 8; ++q) {
                int row = q * 8 + srow;
                *(uint4*)&sTok[cur ^ 1][row * 256 + ((sg ^ (row & 7)) * 8)] = st[q];
            }
        }

        // ---- cross-wave merge + slot store (one thread per token)
        if (tid < 64) {
            float4 m0 = msc[cur][tid][0];
            float v1 = m0.x, v2 = m0.z; int k1 = (int)m0.y, k2 = (int)m0.w;
            #pragma unroll
            for (int ww = 1; ww < 4; ++ww) {
                float4 mw = msc[cur][tid][ww];
                float cv = mw.x; int ck = (int)mw.y;
                if (cv > v1 || (cv == v1 && ck < k1)) { v2 = v1; k2 = k1; v1 = cv; k1 = ck; }
                else if (cv > v2 || (cv == v2 && ck < k2)) { v2 = cv; k2 = ck; }
                cv = mw.z; ck = (int)mw.w;
                if (cv > v1 || (cv == v1 && ck < k1)) { v2 = v1; k2 = k1; v1 = cv; k1 = ck; }
                else if (cv > v2 || (cv == v2 && ck < k2)) { v2 = cv; k2 = ck; }
            }
            int token = tok0 + p * 64 + tid;
            *(float4*)(out + (size_t)token * DM + grp * 4) = (float4){ v1, (float)k1, v2, (float)k2 };
        }
        __syncthreads();   // buf[cur^1] writes + msc reuse safe for next panel
    }
}

// k_gather_mfma: candidates from 64 slots, exact np-f32 re-check, gather, loss
__global__ __launch_bounds__(256) void k_gather_mfma(const float* __restrict__ x,
                                                     const float* __restrict__ cb,
                                                     float* __restrict__ out,
                                                     float* __restrict__ lp) {
    __shared__ float4 xls[4][64];
    __shared__ int candk[4][16];
    __shared__ float bsum[4];

    const int w = threadIdx.x >> 6;
    const int L = threadIdx.x & 63;
    const int t = blockIdx.x * 4 + w;

    const float4 xv = ((const float4*)x)[(size_t)t * 64 + L];
    xls[w][L] = xv;
    const float4 f = ((const float4*)(out + (size_t)t * DM))[L];   // slot L
    __syncthreads();   // drain slot reads before row overwrite

    // x2 (any f32 within ~1e-4 of numpy's: uniform grid shift)
    double dl = (double)xv.x * xv.x + (double)xv.y * xv.y
              + (double)xv.z * xv.z + (double)xv.w * xv.w;
    #pragma unroll
    for (int off = 32; off; off >>= 1) dl += __shfl_xor(dl, off);
    const float x2 = (float)dl;

    float lm = fmaxf(f.x, f.z);
    #pragma unroll
    for (int off = 32; off; off >>= 1) lm = fmaxf(lm, __shfl_xor(lm, off));
    const float thr = lm - MARGIN;

    int ncand = 0;
    #pragma unroll
    for (int p = 0; p < 2; ++p) {
        float vv = p ? f.z : f.x;
        float kf = p ? f.w : f.y;
        unsigned long long bal = __ballot(vv >= thr);
        while (bal) {
            int src = __ffsll(bal) - 1;
            bal &= bal - 1;
            float kv = __shfl(kf, src);
            if (L == 0 && ncand < 16) candk[w][ncand] = (int)kv;
            ncand++;
        }
    }
    if (ncand > 16) ncand = 16;

    int best;
    if (ncand == 1) {
        best = candk[w][0];
    } else {
        const int g = L >> 2, l4 = L & 3;
        float sex = FLT_MAX;
        int   kk  = 0x7fffffff;
        if (g < ncand) {
            kk = candk[w][g];
            const float* xr = (const float*)&xls[w][0];
            const float* cr = cb + (size_t)kk * DM;
            float acc = 0.f;
            {
#pragma clang fp contract(off)
                #pragma unroll 8
                for (int m = 0; m < 64; m++) {
                    float p2 = xr[4 * m + l4] * cr[4 * m + l4];
                    acc = acc + p2;
                }
            }
            float t1 = acc + __shfl_xor(acc, 1);   // fl(s0+s1)/fl(s2+s3)
            float xc = t1 + __shfl_xor(t1, 2);     // np 4-acc SSE combine
            sex = x2 - 2.0f * xc;
        }
        #pragma unroll
        for (int off = 32; off; off >>= 1) {
            float os = __shfl_xor(sex, off);
            int   ok = __shfl_xor(kk, off);
            if (os < sex || (os == sex && ok < kk)) { sex = os; kk = ok; }
        }
        best = kk;
    }

    const float4 cv = ((const float4*)cb)[(size_t)best * 64 + L];
    float4 e, q;
    e.x = cv.x - xv.x; q.x = xv.x + e.x;
    e.y = cv.y - xv.y; q.y = xv.y + e.y;
    e.z = cv.z - xv.z; q.z = xv.z + e.z;
    e.w = cv.w - xv.w; q.w = xv.w + e.w;
    ((float4*)out)[(size_t)t * 64 + L] = q;
    if (L == 0) out[QOFF + t] = (float)best;

    float ls = e.x * e.x + e.y * e.y + e.z * e.z + e.w * e.w;
    #pragma unroll
    for (int off = 32; off; off >>= 1) ls += __shfl_xor(ls, off);
    if (L == 0) bsum[w] = ls;
    __syncthreads();
    if (threadIdx.x == 0)
        lp[blockIdx.x] = bsum[0] + bsum[1] + bsum[2] + bsum[3];
}

// ======================= fallback f32 path (round-2, verified) =======================

#define TM    64
#define TK    64
#define NSPLIT 2
#define KPS   (KC / NSPLIT)
#define LDSW  68

__global__ __launch_bounds__(256, 2) void k_main_f32(const float* __restrict__ x,
                                                     const float* __restrict__ cb,
                                                     float* __restrict__ out) {
    __shared__ float xs[TM * LDSW];
    __shared__ float cs[TK * LDSW];

    const int tid = threadIdx.x;
    const int ty = tid >> 4, tx = tid & 15;
    const int split = blockIdx.x & 1;
    const int tb    = blockIdx.x >> 1;
    const int t0    = tb * TM;
    const int kb0   = split * KPS;
    const int txc   = tx & 7;
    const int srow = tid >> 4;
    const int sc4  = tid & 15;
    const float4* x4  = (const float4*)x;
    const float4* cb4 = (const float4*)cb;

    float mv[4][4];
    int   mi[4][4];
    #pragma unroll
    for (int i = 0; i < 4; i++)
        #pragma unroll
        for (int j = 0; j < 4; j++) { mv[i][j] = -FLT_MAX; mi[i][j] = 0; }

    for (int k0 = 0; k0 < KPS; k0 += TK) {
        float dot[4][4];
        #pragma unroll
        for (int i = 0; i < 4; i++)
            #pragma unroll
            for (int j = 0; j < 4; j++) dot[i][j] = 0.f;

        for (int d0 = 0; d0 < DM; d0 += 64) {
            __syncthreads();
            const int d04 = d0 >> 2;
            #pragma unroll
            for (int r = 0; r < 4; r++) {
                int row = srow + 16 * r;
                float4 xv = x4[(size_t)(t0 + row) * 64 + d04 + sc4];
                *(float4*)&xs[row * LDSW + sc4 * 4] = xv;
                int gc = sc4 ^ ((row >> 2) & 7);
                float4 cv = cb4[(size_t)(kb0 + k0 + row) * 64 + d04 + gc];
                *(float4*)&cs[row * LDSW + sc4 * 4] = cv;
            }
            __syncthreads();

            #pragma unroll
            for (int u = 0; u < 16; u++) {
                float4 xa[4];
                #pragma unroll
                for (int i = 0; i < 4; i++)
                    xa[i] = *(const float4*)&xs[(ty * 4 + i) * LDSW + u * 4];
                const int ww = u ^ txc;
                float4 cv[4];
                #pragma unroll
                for (int j = 0; j < 4; j++)
                    cv[j] = *(const float4*)&cs[(tx * 4 + j) * LDSW + ww * 4];
                #pragma unroll
                for (int i = 0; i < 4; i++)
                    #pragma unroll
                    for (int j = 0; j < 4; j++) {
                        dot[i][j] = fmaf(xa[i].x, cv[j].x, dot[i][j]);
                        dot[i][j] = fmaf(xa[i].y, cv[j].y, dot[i][j]);
                        dot[i][j] = fmaf(xa[i].z, cv[j].z, dot[i][j]);
                        dot[i][j] = fmaf(xa[i].w, cv[j].w, dot[i][j]);
                    }
            }
        }

        const int kk0 = kb0 + k0 + tx * 4;
        #pragma unroll
        for (int i = 0; i < 4; i++)
            #pragma unroll
            for (int j = 0; j < 4; j++) {
                float d = dot[i][j];
                int   kk = kk0 + j;
                if (d > mv[i][3]) {
                    if (d > mv[i][1]) {
                        if (d > mv[i][0]) {
                            mv[i][3]=mv[i][2]; mi[i][3]=mi[i][2];
                            mv[i][2]=mv[i][1]; mi[i][2]=mi[i][1];
                            mv[i][1]=mv[i][0]; mi[i][1]=mi[i][0];
                            mv[i][0]=d;        mi[i][0]=kk;
                        } else {
                            mv[i][3]=mv[i][2]; mi[i][3]=mi[i][2];
                            mv[i][2]=mv[i][1]; mi[i][2]=mi[i][1];
                            mv[i][1]=d;        mi[i][1]=kk;
                        }
                    } else {
                        if (d > mv[i][2]) {
                            mv[i][3]=mv[i][2]; mi[i][3]=mi[i][2];
                            mv[i][2]=d;        mi[i][2]=kk;
                        } else {
                            mv[i][3]=d;        mi[i][3]=kk;
                        }
                    }
                }
            }
    }

    #pragma unroll
    for (int i = 0; i < 4; i++) {
        int t = t0 + ty * 4 + i;
        float4 v4 = { mv[i][0], mv[i][1], mv[i][2], mv[i][3] };
        float4 k4 = { (float)mi[i][0], (float)mi[i][1], (float)mi[i][2], (float)mi[i][3] };
        float4* dst = (float4*)(out + (size_t)t * DM + (split * 16 + tx) * 8);
        dst[0] = v4;
        dst[1] = k4;
    }
}

__global__ __launch_bounds__(256) void k_gather_f32(const float* __restrict__ x,
                                                    const float* __restrict__ cb,
                                                    float* __restrict__ out,
                                                    float* __restrict__ lp) {
    __shared__ float4 xls[4][64];
    __shared__ int candk[4][20];
    __shared__ float bsum[4];

    const int w = threadIdx.x >> 6;
    const int L = threadIdx.x & 63;
    const int t = blockIdx.x * 4 + w;

    const float4 xv = ((const float4*)x)[(size_t)t * 64 + L];
    xls[w][L] = xv;
    const float4 f = ((const float4*)(out + (size_t)t * DM))[L];
    const bool even = ((L & 1) == 0);

    double dl = (double)xv.x * xv.x + (double)xv.y * xv.y
              + (double)xv.z * xv.z + (double)xv.w * xv.w;
    #pragma unroll
    for (int off = 32; off; off >>= 1) dl += __shfl_xor(dl, off);
    const float x2 = (float)dl;

    float lm = even ? fmaxf(fmaxf(f.x, f.y), fmaxf(f.z, f.w)) : -FLT_MAX;
    #pragma unroll
    for (int off = 32; off; off >>= 1) lm = fmaxf(lm, __shfl_xor(lm, off));
    const float thr = lm - 5e-5f;

    int ncand = 0;
    #pragma unroll
    for (int j = 0; j < 4; j++) {
        float vj = (j == 0) ? f.x : (j == 1) ? f.y : (j == 2) ? f.z : f.w;
        bool flag = even && (vj >= thr);
        unsigned long long bal = __ballot(flag);
        while (bal) {
            int src = __ffsll(bal) - 1;
            bal &= bal - 1;
            float kv = __shfl(vj, src + 1);
            if (L == 0 && ncand < 20) candk[w][ncand] = (int)kv;
            ncand++;
        }
    }
    if (ncand > 16) ncand = 16;

    int best;
    if (ncand == 1) {
        best = candk[w][0];
    } else {
        const int g = L >> 2, l4 = L & 3;
        float sex = FLT_MAX;
        int   kk  = 0x7fffffff;
        if (g < ncand) {
            kk = candk[w][g];
            const float* xr = (const float*)&xls[w][0];
            const float* cr = cb + (size_t)kk * DM;
            float acc = 0.f;
            {
#pragma clang fp contract(off)
                #pragma unroll 8
                for (int m = 0; m < 64; m++) {
                    float p = xr[4 * m + l4] * cr[4 * m + l4];
                    acc = acc + p;
                }
            }
            float t1 = acc + __shfl_xor(acc, 1);
            float xc = t1 + __shfl_xor(t1, 2);
            sex = x2 - 2.0f * xc;
        }
        #pragma unroll
        for (int off = 32; off; off >>= 1) {
            float os = __shfl_xor(sex, off);
            int   ok = __shfl_xor(kk, off);
            if (os < sex || (os == sex && ok < kk)) { sex = os; kk = ok; }
        }
        best = kk;
    }

    const float4 cv = ((const float4*)cb)[(size_t)best * 64 + L];
    float4 e, q;
    e.x = cv.x - xv.x; q.x = xv.x + e.x;
    e.y = cv.y - xv.y; q.y = xv.y + e.y;
    e.z = cv.z - xv.z; q.z = xv.z + e.z;
    e.w = cv.w - xv.w; q.w = xv.w + e.w;
    ((float4*)out)[(size_t)t * 64 + L] = q;
    if (L == 0) out[QOFF + t] = (float)best;

    float ls = e.x * e.x + e.y * e.y + e.z * e.z + e.w * e.w;
    #pragma unroll
    for (int off = 32; off; off >>= 1) ls += __shfl_xor(ls, off);
    if (L == 0) bsum[w] = ls;
    __syncthreads();
    if (threadIdx.x == 0)
        lp[blockIdx.x] = bsum[0] + bsum[1] + bsum[2] + bsum[3];
}

// ---------------- shared loss finalize ----------------
__global__ __launch_bounds__(256) void k_loss(const float* __restrict__ lp,
                                              float* __restrict__ out) {
    __shared__ double sd[256];
    double s = 0.0;
    for (int i = threadIdx.x; i < BT / 4; i += 256) s += (double)lp[i];
    sd[threadIdx.x] = s;
    __syncthreads();
    for (int st = 128; st; st >>= 1) {
        if (threadIdx.x < st) sd[threadIdx.x] += sd[threadIdx.x + st];
        __syncthreads();
    }
    if (threadIdx.x == 0)
        out[LOFF] = (float)(2.0 * sd[0] / (double)QOFF);
}

extern "C" void kernel_launch(void* const* d_in, const int* in_sizes, int n_in,
                              void* d_out, int out_size, void* d_ws, size_t ws_size,
                              hipStream_t stream) {
    const float* x  = (const float*)d_in[0];
    const float* cb = (const float*)d_in[1];
    float* out = (float*)d_out;

    if (ws_size >= (size_t)WS_NEED) {
        ushort* wsu = (ushort*)d_ws;
        float*  lp  = (float*)((char*)d_ws + WS_LP_BYTES);
        k_cvt        <<<6144, 256, 0, stream>>>(x, cb, wsu);
        k_main_mfma  <<<512,  256, 0, stream>>>(wsu, out);
        k_gather_mfma<<<BT / 4, 256, 0, stream>>>(x, cb, out, lp);
        k_loss       <<<1,    256, 0, stream>>>(lp, out);
    } else {
        float* lp = (float*)d_ws;
        k_main_f32  <<<(BT / TM) * NSPLIT, 256, 0, stream>>>(x, cb, out);
        k_gather_f32<<<BT / 4,             256, 0, stream>>>(x, cb, out, lp);
        k_loss      <<<1,                  256, 0, stream>>>(lp, out);
    }
}